// Round 7
// baseline (226.226 us; speedup 1.0000x reference)
//
#include <hip/hip_runtime.h>

// MultiLabelSoftMax: B=4096 rows, C=8192 classes, K=8 positives/row.
// out = (1/(B*K)) * sum_{b,k} [ log(exp(p_bk) + sum_neg_b) - p_bk ]
//
// Round-7: R6 kernel UNCHANGED (node 1) + a measurement probe (node 2)
// that streams a disjoint cold 134 MB region of d_ws with the identical
// stage-8 float4 body. dur_us delta vs R6 (188.8) = true cost of one
// 134 MB streaming pass. Adjudicates: floor=135/kernel=53 (H1) vs
// floor=169/kernel=20 (H2). Probe writes only into d_ws (never d_out),
// so correctness is unaffected.

constexpr int B = 4096;
constexpr int C = 8192;
constexpr int K = 8;
constexpr int BLOCK = 1024;                // 16 waves of 64
constexpr int WPB = BLOCK / 64;            // 16 rows per block
constexpr int GRID = B / WPB;              // 256 blocks = 1/CU
constexpr int V4_PER_LANE = C / 4 / 64;    // 32 float4 per lane
constexpr int STAGE = 8;                   // loads in flight per stage

__global__ __launch_bounds__(BLOCK, 4)
void mlsm_kernel(const float* __restrict__ pred,
                 const int* __restrict__ labels,
                 float* __restrict__ out) {
    const int wave = threadIdx.x >> 6;
    const int lane = threadIdx.x & 63;
    const int b    = blockIdx.x * WPB + wave;
    const float* row = pred + (size_t)b * C;
    const float4* row4 = reinterpret_cast<const float4*>(row);

    __shared__ float wave_term[WPB];

    float p = 0.0f;
    if (lane < K) p = row[labels[b * K + lane]];

    float s0 = 0.f, s1 = 0.f, s2 = 0.f, s3 = 0.f;
#pragma unroll
    for (int g = 0; g < V4_PER_LANE / STAGE; ++g) {
        float4 v[STAGE];
#pragma unroll
        for (int i = 0; i < STAGE; ++i)
            v[i] = row4[lane + (g * STAGE + i) * 64];
#pragma unroll
        for (int i = 0; i < STAGE; ++i) {
            s0 += __expf(v[i].x);
            s1 += __expf(v[i].y);
            s2 += __expf(v[i].z);
            s3 += __expf(v[i].w);
        }
    }
    float s = (s0 + s1) + (s2 + s3);

#pragma unroll
    for (int m = 1; m < 64; m <<= 1)
        s += __shfl_xor(s, m, 64);

    if (lane < K) {
        const float e = __expf(p);
        float sum_pos = e;
#pragma unroll
        for (int m = 1; m < K; m <<= 1)
            sum_pos += __shfl_xor(sum_pos, m, K);

        const float sum_neg = s - sum_pos;
        float term = __logf(e + sum_neg) - p;
#pragma unroll
        for (int m = 1; m < K; m <<= 1)
            term += __shfl_xor(term, m, K);

        if (lane == 0) wave_term[wave] = term;
    }
    __syncthreads();

    if (threadIdx.x < WPB) {
        float t = wave_term[threadIdx.x];
#pragma unroll
        for (int m = 1; m < WPB; m <<= 1)
            t += __shfl_xor(t, m, WPB);
        if (threadIdx.x == 0)
            atomicAdd(out, t * (1.0f / (float)(B * K)));
    }
}

// Probe: identical streaming body over 134 MB of cold d_ws; dummy sums
// written 256 MiB further into d_ws. Never touches d_out.
__global__ __launch_bounds__(BLOCK, 4)
void mlsm_probe(const float* __restrict__ src,
                float* __restrict__ dummy) {
    const int wave = threadIdx.x >> 6;
    const int lane = threadIdx.x & 63;
    const int b    = blockIdx.x * WPB + wave;
    const float4* row4 =
        reinterpret_cast<const float4*>(src + (size_t)b * C);

    float s0 = 0.f, s1 = 0.f, s2 = 0.f, s3 = 0.f;
#pragma unroll
    for (int g = 0; g < V4_PER_LANE / STAGE; ++g) {
        float4 v[STAGE];
#pragma unroll
        for (int i = 0; i < STAGE; ++i)
            v[i] = row4[lane + (g * STAGE + i) * 64];
#pragma unroll
        for (int i = 0; i < STAGE; ++i) {
            s0 += __expf(v[i].x);
            s1 += __expf(v[i].y);
            s2 += __expf(v[i].z);
            s3 += __expf(v[i].w);
        }
    }
    float s = (s0 + s1) + (s2 + s3);

#pragma unroll
    for (int m = 1; m < 64; m <<= 1)
        s += __shfl_xor(s, m, 64);

    if (lane == 0) dummy[b] = s;
}

extern "C" void kernel_launch(void* const* d_in, const int* in_sizes, int n_in,
                              void* d_out, int out_size, void* d_ws, size_t ws_size,
                              hipStream_t stream) {
    const float* pred = (const float*)d_in[0];
    const int* labels = (const int*)d_in[1];
    float* out        = (float*)d_out;

    mlsm_kernel<<<GRID, BLOCK, 0, stream>>>(pred, labels, out);

    // Probe reads the first 134 MB of d_ws (cold, poisoned -3e-13),
    // writes 4096 dummy floats at the 256 MiB mark (ws is 512 MiB).
    const float* src = (const float*)d_ws;
    float* dummy = (float*)((char*)d_ws + ws_size / 2);
    mlsm_probe<<<GRID, BLOCK, 0, stream>>>(src, dummy);
}